// Round 1
// baseline (567.531 us; speedup 1.0000x reference)
//
#include <hip/hip_runtime.h>
#include <hip/hip_bf16.h>
#include <stdint.h>

#define TT 2048
#define DD 1024
#define HH 16
#define HDIM 64
#define BB 4
#define MROWS 8192   // B*T

typedef __attribute__((ext_vector_type(8))) short short8;
typedef __attribute__((ext_vector_type(4))) float floatx4;

__device__ __forceinline__ ushort f2bf(float f){
  uint32_t u = __builtin_bit_cast(uint32_t, f);
  u = u + 0x7fffu + ((u >> 16) & 1u);   // RNE
  return (ushort)(u >> 16);
}

__device__ __forceinline__ void gld16(const void* g, void* l){
  __builtin_amdgcn_global_load_lds((const __attribute__((address_space(1))) uint32_t*)g,
                                   (__attribute__((address_space(3))) uint32_t*)l, 16, 0, 0);
}

// ---------------- fp32 -> bf16 conversion ----------------
__global__ void cvt_bf16(const float* __restrict__ src, ushort* __restrict__ dst, int n4){
  int i = blockIdx.x*blockDim.x + threadIdx.x;
  if (i < n4){
    float4 v = ((const float4*)src)[i];
    ushort4 o;
    o.x = f2bf(v.x); o.y = f2bf(v.y); o.z = f2bf(v.z); o.w = f2bf(v.w);
    ((ushort4*)dst)[i] = o;
  }
}

// ---------------- QKV projection GEMM: C = A @ W^T + b ----------------
// A: [8192][1024] bf16 row-major, W: [1024][1024] bf16 row-major (B^T form).
// Output written head-split: [B,H,T,HD] bf16. Q additionally scaled by 0.125.
__global__ __launch_bounds__(256) void qkv_gemm(
    const ushort* __restrict__ A, const ushort* __restrict__ Wall,
    const float* __restrict__ bq, const float* __restrict__ bk, const float* __restrict__ bv,
    ushort* __restrict__ Qo, ushort* __restrict__ Ko, ushort* __restrict__ Vo)
{
  __shared__ __align__(16) ushort sA[128*64];
  __shared__ __align__(16) ushort sB[128*64];
  const int mat = blockIdx.z;
  const ushort* W = Wall + (size_t)mat*DD*DD;
  const float* bias = (mat==0)? bq : (mat==1? bk : bv);
  ushort* out = (mat==0)? Qo : (mat==1? Ko : Vo);
  const float oscale = (mat==0)? 0.125f : 1.0f;
  const int m0 = blockIdx.x*128, n0 = blockIdx.y*128;
  const int tid = threadIdx.x, lane = tid & 63, wid = tid >> 6;
  const int wm = (wid>>1)*64, wn = (wid&1)*64;
  const int c = lane & 15, g = lane >> 4;
  const int srow = lane >> 3;          // 0..7 within staging chunk
  const int scol = (lane & 7) * 8;     // element col within K-slab

  floatx4 acc[4][4];
  #pragma unroll
  for (int i=0;i<4;i++)
    #pragma unroll
    for(int j=0;j<4;j++) acc[i][j] = (floatx4){0.f,0.f,0.f,0.f};

  for (int k0 = 0; k0 < DD; k0 += 64){
    #pragma unroll
    for (int j=0;j<4;j++){
      int chunk = wid*4 + j;               // wave-uniform
      int row = chunk*8 + srow;
      gld16(A + (size_t)(m0+row)*DD + k0 + scol, sA + chunk*512);
      gld16(W + (size_t)(n0+row)*DD + k0 + scol, sB + chunk*512);
    }
    __syncthreads();   // drains vmcnt: staging complete
    #pragma unroll
    for (int ch=0; ch<2; ++ch){
      short8 af[4], bfr[4];
      #pragma unroll
      for (int mf=0; mf<4; ++mf)
        af[mf] = *(const short8*)(sA + (wm + mf*16 + c)*64 + ch*32 + g*8);
      #pragma unroll
      for (int nf=0; nf<4; ++nf)
        bfr[nf] = *(const short8*)(sB + (wn + nf*16 + c)*64 + ch*32 + g*8);
      #pragma unroll
      for (int mf=0; mf<4; ++mf)
        #pragma unroll
        for (int nf=0; nf<4; ++nf)
          acc[mf][nf] = __builtin_amdgcn_mfma_f32_16x16x32_bf16(af[mf], bfr[nf], acc[mf][nf], 0,0,0);
    }
    __syncthreads();   // all waves done reading before next stage overwrites
  }
  // epilogue: C/D layout col=lane&15, row=(lane>>4)*4+reg
  #pragma unroll
  for (int nf=0; nf<4; ++nf){
    int col = n0 + wn + nf*16 + c;
    float bval = bias[col];
    int h = col >> 6, hd = col & 63;
    #pragma unroll
    for (int mf=0; mf<4; ++mf){
      int rowb = m0 + wm + mf*16 + g*4;
      #pragma unroll
      for (int r=0; r<4; ++r){
        int row = rowb + r;
        int b = row >> 11, t = row & (TT-1);
        float v = (acc[mf][nf][r] + bval) * oscale;
        out[((size_t)(b*HH + h)*TT + t)*HDIM + hd] = f2bf(v);
      }
    }
  }
}

// ---------------- V transpose: [B,H,T,HD] -> [B,H,HD,T] ----------------
__global__ __launch_bounds__(256) void vtranspose(const ushort* __restrict__ V, ushort* __restrict__ VT){
  __shared__ __align__(16) ushort tile[64][72];
  int bh = blockIdx.y, t0 = blockIdx.x*64;
  int tid = threadIdx.x;
  int r = tid >> 3, cb = (tid & 7)*8;
  for (int rr = r; rr < 64; rr += 32)
    *(short8*)&tile[rr][cb] = *(const short8*)(V + ((size_t)bh*TT + t0 + rr)*HDIM + cb);
  __syncthreads();
  for (int hh = r; hh < 64; hh += 32){
    __attribute__((aligned(16))) ushort tmp[8];
    #pragma unroll
    for (int i=0;i<8;i++) tmp[i] = tile[cb+i][hh];
    *(short8*)(VT + ((size_t)bh*HDIM + hh)*TT + t0 + cb) = *(short8*)&tmp[0];
  }
}

// ---------------- causal flash attention ----------------
// grid: (T/64, B*H), 4 waves/block, each wave owns 16 q rows.
__global__ __launch_bounds__(256) void attn_fwd(
    const ushort* __restrict__ Q, const ushort* __restrict__ K, const ushort* __restrict__ VT,
    const float* __restrict__ amask, float* __restrict__ O)
{
  __shared__ __align__(16) ushort sP[4][16][72];  // wave-private P tiles, padded stride
  const int bh = blockIdx.y, b = bh >> 4, h = bh & 15;
  const int q0 = blockIdx.x * 64;
  const int tid = threadIdx.x, lane = tid & 63, w = tid >> 6;
  const int c = lane & 15, g = lane >> 4;
  const int qw = q0 + w*16;

  // Q A-fragments (K=64 -> 2 chunks), Q pre-scaled by 0.125 at projection
  short8 qf[2];
  #pragma unroll
  for (int ch=0; ch<2; ++ch)
    qf[ch] = *(const short8*)(Q + ((size_t)bh*TT + qw + c)*HDIM + ch*32 + g*8);

  floatx4 oacc[4];
  #pragma unroll
  for (int i=0;i<4;i++) oacc[i] = (floatx4){0.f,0.f,0.f,0.f};
  float m_r[4] = {-1e30f,-1e30f,-1e30f,-1e30f};
  float l_r[4] = {0.f,0.f,0.f,0.f};

  const int ntile = q0/64 + 1;   // uniform across block (barrier-safe)
  for (int it=0; it<ntile; ++it){
    const int kv0 = it*64;
    const bool active = (kv0 <= qw + 15);
    if (active){
      floatx4 sacc[4];
      #pragma unroll
      for (int i=0;i<4;i++) sacc[i] = (floatx4){0.f,0.f,0.f,0.f};
      #pragma unroll
      for (int ch=0; ch<2; ++ch){
        #pragma unroll
        for (int nt=0; nt<4; ++nt){
          short8 kf = *(const short8*)(K + ((size_t)bh*TT + kv0 + nt*16 + c)*HDIM + ch*32 + g*8);
          sacc[nt] = __builtin_amdgcn_mfma_f32_16x16x32_bf16(qf[ch], kf, sacc[nt], 0,0,0);
        }
      }
      float amv[4];
      #pragma unroll
      for (int nt=0; nt<4; ++nt) amv[nt] = amask[(size_t)b*TT + kv0 + nt*16 + c];
      float p[4][4];
      #pragma unroll
      for (int r=0; r<4; ++r){
        const int qr = qw + g*4 + r;
        float mx = -1e30f;
        #pragma unroll
        for (int nt=0; nt<4; ++nt){
          float s = sacc[nt][r] + amv[nt];
          if (kv0 + nt*16 + c > qr) s = -1e30f;   // causal
          p[nt][r] = s;
          mx = fmaxf(mx, s);
        }
        mx = fmaxf(mx, __shfl_xor(mx, 1));
        mx = fmaxf(mx, __shfl_xor(mx, 2));
        mx = fmaxf(mx, __shfl_xor(mx, 4));
        mx = fmaxf(mx, __shfl_xor(mx, 8));
        float mnew = fmaxf(m_r[r], mx);
        float scal = __expf(m_r[r] - mnew);
        m_r[r] = mnew;
        float ps = 0.f;
        #pragma unroll
        for (int nt=0; nt<4; ++nt){
          float e = __expf(p[nt][r] - mnew);
          p[nt][r] = e;
          ps += e;
        }
        ps += __shfl_xor(ps, 1);
        ps += __shfl_xor(ps, 2);
        ps += __shfl_xor(ps, 4);
        ps += __shfl_xor(ps, 8);
        l_r[r] = l_r[r]*scal + ps;
        #pragma unroll
        for (int d=0; d<4; ++d) oacc[d][r] *= scal;
      }
      #pragma unroll
      for (int r=0; r<4; ++r)
        #pragma unroll
        for (int nt=0; nt<4; ++nt)
          sP[w][g*4+r][nt*16+c] = f2bf(p[nt][r]);
    }
    __syncthreads();   // P writes visible (lgkmcnt drained)
    if (active){
      short8 pa[2];
      #pragma unroll
      for (int ch=0; ch<2; ++ch)
        pa[ch] = *(const short8*)(&sP[w][c][ch*32 + g*8]);
      #pragma unroll
      for (int d=0; d<4; ++d){
        #pragma unroll
        for (int ch=0; ch<2; ++ch){
          short8 vf = *(const short8*)(VT + ((size_t)bh*HDIM + d*16 + c)*TT + kv0 + ch*32 + g*8);
          oacc[d] = __builtin_amdgcn_mfma_f32_16x16x32_bf16(pa[ch], vf, oacc[d], 0,0,0);
        }
      }
    }
    __syncthreads();   // before next tile overwrites sP
  }
  #pragma unroll
  for (int d=0; d<4; ++d){
    #pragma unroll
    for (int r=0; r<4; ++r){
      int qr = qw + g*4 + r;
      O[((size_t)b*TT + qr)*DD + h*HDIM + d*16 + c] = oacc[d][r] / l_r[r];
    }
  }
}

extern "C" void kernel_launch(void* const* d_in, const int* in_sizes, int n_in,
                              void* d_out, int out_size, void* d_ws, size_t ws_size,
                              hipStream_t stream){
  const float* hs    = (const float*)d_in[0];
  const float* amask = (const float*)d_in[1];
  const float* Wq    = (const float*)d_in[2];
  const float* bq    = (const float*)d_in[3];
  const float* Wk    = (const float*)d_in[4];
  const float* bk    = (const float*)d_in[5];
  const float* Wv    = (const float*)d_in[6];
  const float* bv    = (const float*)d_in[7];
  float* out = (float*)d_out;

  ushort* hsb = (ushort*)d_ws;                    // [8192][1024] bf16
  ushort* wb  = hsb + (size_t)MROWS*DD;           // 3x [1024][1024] bf16
  ushort* qb  = wb  + (size_t)3*DD*DD;            // [B,H,T,HD]
  ushort* kb  = qb  + (size_t)MROWS*DD;
  ushort* vb  = kb  + (size_t)MROWS*DD;
  ushort* vtb = vb  + (size_t)MROWS*DD;           // [B,H,HD,T]

  cvt_bf16<<<(MROWS*DD/4)/256, 256, 0, stream>>>(hs, hsb, MROWS*DD/4);
  cvt_bf16<<<(DD*DD/4)/256, 256, 0, stream>>>(Wq, wb,            DD*DD/4);
  cvt_bf16<<<(DD*DD/4)/256, 256, 0, stream>>>(Wk, wb + DD*DD,    DD*DD/4);
  cvt_bf16<<<(DD*DD/4)/256, 256, 0, stream>>>(Wv, wb + 2*DD*DD,  DD*DD/4);

  qkv_gemm<<<dim3(MROWS/128, DD/128, 3), 256, 0, stream>>>(hsb, wb, bq, bk, bv, qb, kb, vb);
  vtranspose<<<dim3(TT/64, BB*HH), 256, 0, stream>>>(vb, vtb);
  attn_fwd<<<dim3(TT/64, BB*HH), 256, 0, stream>>>(qb, kb, vtb, amask, out);
}

// Round 2
// 374.581 us; speedup vs baseline: 1.5151x; 1.5151x over previous
//
#include <hip/hip_runtime.h>
#include <hip/hip_bf16.h>
#include <stdint.h>

#define TT 2048
#define DD 1024
#define HH 16
#define HDIM 64
#define BB 4
#define MROWS 8192   // B*T

typedef __attribute__((ext_vector_type(8))) short short8;
typedef __attribute__((ext_vector_type(4))) float floatx4;

__device__ __forceinline__ ushort f2bf(float f){
  uint32_t u = __builtin_bit_cast(uint32_t, f);
  u = u + 0x7fffu + ((u >> 16) & 1u);   // RNE
  return (ushort)(u >> 16);
}

__device__ __forceinline__ uint32_t cvtpk(float lo, float hi){
  uint32_t r;
  asm("v_cvt_pk_bf16_f32 %0, %1, %2" : "=v"(r) : "v"(lo), "v"(hi));
  return r;
}

__device__ __forceinline__ void gld16(const void* g, void* l){
  __builtin_amdgcn_global_load_lds((const __attribute__((address_space(1))) uint32_t*)g,
                                   (__attribute__((address_space(3))) uint32_t*)l, 16, 0, 0);
}

// ---------------- fp32 -> bf16 conversion ----------------
__global__ void cvt_bf16(const float* __restrict__ src, ushort* __restrict__ dst, int n4){
  int i = blockIdx.x*blockDim.x + threadIdx.x;
  if (i < n4){
    float4 v = ((const float4*)src)[i];
    ushort4 o;
    o.x = f2bf(v.x); o.y = f2bf(v.y); o.z = f2bf(v.z); o.w = f2bf(v.w);
    ((ushort4*)dst)[i] = o;
  }
}

// ---------------- QKV projection GEMM: C = A @ W^T + b ----------------
__global__ __launch_bounds__(256) void qkv_gemm(
    const ushort* __restrict__ A, const ushort* __restrict__ Wall,
    const float* __restrict__ bq, const float* __restrict__ bk, const float* __restrict__ bv,
    ushort* __restrict__ Qo, ushort* __restrict__ Ko, ushort* __restrict__ Vo)
{
  __shared__ __align__(16) ushort sA[128*64];
  __shared__ __align__(16) ushort sB[128*64];
  const int mat = blockIdx.z;
  const ushort* W = Wall + (size_t)mat*DD*DD;
  const float* bias = (mat==0)? bq : (mat==1? bk : bv);
  ushort* out = (mat==0)? Qo : (mat==1? Ko : Vo);
  const float oscale = (mat==0)? 0.125f : 1.0f;
  const int m0 = blockIdx.x*128, n0 = blockIdx.y*128;
  const int tid = threadIdx.x, lane = tid & 63, wid = tid >> 6;
  const int wm = (wid>>1)*64, wn = (wid&1)*64;
  const int c = lane & 15, g = lane >> 4;
  const int srow = lane >> 3;
  const int scol = (lane & 7) * 8;

  floatx4 acc[4][4];
  #pragma unroll
  for (int i=0;i<4;i++)
    #pragma unroll
    for(int j=0;j<4;j++) acc[i][j] = (floatx4){0.f,0.f,0.f,0.f};

  for (int k0 = 0; k0 < DD; k0 += 64){
    #pragma unroll
    for (int j=0;j<4;j++){
      int chunk = wid*4 + j;
      int row = chunk*8 + srow;
      gld16(A + (size_t)(m0+row)*DD + k0 + scol, sA + chunk*512);
      gld16(W + (size_t)(n0+row)*DD + k0 + scol, sB + chunk*512);
    }
    __syncthreads();
    #pragma unroll
    for (int ch=0; ch<2; ++ch){
      short8 af[4], bfr[4];
      #pragma unroll
      for (int mf=0; mf<4; ++mf)
        af[mf] = *(const short8*)(sA + (wm + mf*16 + c)*64 + ch*32 + g*8);
      #pragma unroll
      for (int nf=0; nf<4; ++nf)
        bfr[nf] = *(const short8*)(sB + (wn + nf*16 + c)*64 + ch*32 + g*8);
      #pragma unroll
      for (int mf=0; mf<4; ++mf)
        #pragma unroll
        for (int nf=0; nf<4; ++nf)
          acc[mf][nf] = __builtin_amdgcn_mfma_f32_16x16x32_bf16(af[mf], bfr[nf], acc[mf][nf], 0,0,0);
    }
    __syncthreads();
  }
  #pragma unroll
  for (int nf=0; nf<4; ++nf){
    int col = n0 + wn + nf*16 + c;
    float bval = bias[col];
    int h = col >> 6, hd = col & 63;
    #pragma unroll
    for (int mf=0; mf<4; ++mf){
      int rowb = m0 + wm + mf*16 + g*4;
      #pragma unroll
      for (int r=0; r<4; ++r){
        int row = rowb + r;
        int b = row >> 11, t = row & (TT-1);
        float v = (acc[mf][nf][r] + bval) * oscale;
        out[((size_t)(b*HH + h)*TT + t)*HDIM + hd] = f2bf(v);
      }
    }
  }
}

// ---------------- V transpose: [B,H,T,HD] -> [B,H,HD,T] ----------------
__global__ __launch_bounds__(256) void vtranspose(const ushort* __restrict__ V, ushort* __restrict__ VT){
  __shared__ __align__(16) ushort tile[64][72];
  int bh = blockIdx.y, t0 = blockIdx.x*64;
  int tid = threadIdx.x;
  int r = tid >> 3, cb = (tid & 7)*8;
  for (int rr = r; rr < 64; rr += 32)
    *(short8*)&tile[rr][cb] = *(const short8*)(V + ((size_t)bh*TT + t0 + rr)*HDIM + cb);
  __syncthreads();
  for (int hh = r; hh < 64; hh += 32){
    __attribute__((aligned(16))) ushort tmp[8];
    #pragma unroll
    for (int i=0;i<8;i++) tmp[i] = tile[cb+i][hh];
    *(short8*)(VT + ((size_t)bh*HDIM + hh)*TT + t0 + cb) = *(short8*)&tmp[0];
  }
}

// ---------------- causal flash attention (swapped operands, barrier-free) ----
// grid: (16, B*H), 4 waves/block. Block x handles q-tiles {x, 31-x} (uniform work).
// Swapped QK^T: sacc = mfma(K,Q) -> lane holds S[kv = kv0+nt*16+g*4+r][q = qw + (lane&15)]
// Swapped PV:   oacc = mfma(VT,P^T) -> lane holds O[q = qw+c][hd = d*16+g*4+r]
// Softmax state (m,l) is per-lane (one q row per lane group), no cross-lane broadcast.
__device__ __forceinline__ void attn_strip(
    int qtile, int bh, int b, int h, int w, int c, int g,
    const ushort* __restrict__ Q, const ushort* __restrict__ K, const ushort* __restrict__ VT,
    const float* __restrict__ amask, float* __restrict__ O, uint32_t* __restrict__ sPw)
{
  const int qw = qtile*64 + w*16;
  const int qmy = qw + c;

  short8 qf[2];
  #pragma unroll
  for (int ch=0; ch<2; ++ch)
    qf[ch] = *(const short8*)(Q + ((size_t)bh*TT + qmy)*HDIM + ch*32 + g*8);

  floatx4 oacc[4];
  #pragma unroll
  for (int i=0;i<4;i++) oacc[i] = (floatx4){0.f,0.f,0.f,0.f};
  float m = -1e30f, l = 0.f;

  const int ntile = qtile + 1;
  for (int it=0; it<ntile; ++it){
    const int kv0 = it*64;
    floatx4 sacc[4];
    #pragma unroll
    for (int i=0;i<4;i++) sacc[i] = (floatx4){0.f,0.f,0.f,0.f};
    #pragma unroll
    for (int ch=0; ch<2; ++ch){
      #pragma unroll
      for (int nt=0; nt<4; ++nt){
        short8 kf = *(const short8*)(K + ((size_t)bh*TT + kv0 + nt*16 + c)*HDIM + ch*32 + g*8);
        sacc[nt] = __builtin_amdgcn_mfma_f32_16x16x32_bf16(kf, qf[ch], sacc[nt], 0,0,0);
      }
    }
    // softmax: each lane owns 16 kv scores of q row qmy
    float p[4][4];
    float mx = -1e30f;
    #pragma unroll
    for (int nt=0; nt<4; ++nt){
      float4 am4 = *(const float4*)(amask + (size_t)b*TT + kv0 + nt*16 + g*4);
      #pragma unroll
      for (int r=0; r<4; ++r){
        int kv = kv0 + nt*16 + g*4 + r;
        float s = sacc[nt][r] + ((const float*)&am4)[r];
        if (kv > qmy) s = -1e30f;
        p[nt][r] = s;
        mx = fmaxf(mx, s);
      }
    }
    mx = fmaxf(mx, __shfl_xor(mx, 16));
    mx = fmaxf(mx, __shfl_xor(mx, 32));
    float mnew = fmaxf(m, mx);
    float scal = __expf(m - mnew);
    m = mnew;
    float ps = 0.f;
    #pragma unroll
    for (int nt=0; nt<4; ++nt)
      #pragma unroll
      for (int r=0; r<4; ++r){
        float e = __expf(p[nt][r] - mnew);
        p[nt][r] = e;
        ps += e;
      }
    ps += __shfl_xor(ps, 16);
    ps += __shfl_xor(ps, 32);
    l = l*scal + ps;
    #pragma unroll
    for (int d=0; d<4; ++d)
      #pragma unroll
      for (int r=0; r<4; ++r) oacc[d][r] *= scal;
    // pack P to bf16 pairs, bounce through wave-private LDS (no barrier needed)
    #pragma unroll
    for (int nt=0; nt<4; ++nt){
      sPw[c*36 + 8*nt + 2*g + 0] = cvtpk(p[nt][0], p[nt][1]);
      sPw[c*36 + 8*nt + 2*g + 1] = cvtpk(p[nt][2], p[nt][3]);
    }
    short8 pb[2];
    #pragma unroll
    for (int ch=0; ch<2; ++ch)
      pb[ch] = *(const short8*)(sPw + c*36 + 16*ch + 4*g);
    #pragma unroll
    for (int d=0; d<4; ++d){
      #pragma unroll
      for (int ch=0; ch<2; ++ch){
        short8 vf = *(const short8*)(VT + ((size_t)bh*HDIM + d*16 + c)*TT + kv0 + ch*32 + g*8);
        oacc[d] = __builtin_amdgcn_mfma_f32_16x16x32_bf16(vf, pb[ch], oacc[d], 0,0,0);
      }
    }
  }
  float rl = 1.f / l;
  #pragma unroll
  for (int d=0; d<4; ++d){
    float4 st;
    st.x = oacc[d][0]*rl; st.y = oacc[d][1]*rl; st.z = oacc[d][2]*rl; st.w = oacc[d][3]*rl;
    *(float4*)(O + ((size_t)b*TT + qmy)*DD + h*HDIM + d*16 + g*4) = st;
  }
}

__global__ __launch_bounds__(256) void attn_fwd(
    const ushort* __restrict__ Q, const ushort* __restrict__ K, const ushort* __restrict__ VT,
    const float* __restrict__ amask, float* __restrict__ O)
{
  __shared__ __align__(16) uint32_t sP[4][16*36];
  const int bh = blockIdx.y, b = bh >> 4, h = bh & 15;
  const int tid = threadIdx.x, lane = tid & 63, w = tid >> 6;
  const int c = lane & 15, g = lane >> 4;
  uint32_t* sPw = sP[w];

  attn_strip(blockIdx.x,      bh, b, h, w, c, g, Q, K, VT, amask, O, sPw);
  attn_strip(31 - blockIdx.x, bh, b, h, w, c, g, Q, K, VT, amask, O, sPw);
}

extern "C" void kernel_launch(void* const* d_in, const int* in_sizes, int n_in,
                              void* d_out, int out_size, void* d_ws, size_t ws_size,
                              hipStream_t stream){
  const float* hs    = (const float*)d_in[0];
  const float* amask = (const float*)d_in[1];
  const float* Wq    = (const float*)d_in[2];
  const float* bq    = (const float*)d_in[3];
  const float* Wk    = (const float*)d_in[4];
  const float* bk    = (const float*)d_in[5];
  const float* Wv    = (const float*)d_in[6];
  const float* bv    = (const float*)d_in[7];
  float* out = (float*)d_out;

  ushort* hsb = (ushort*)d_ws;                    // [8192][1024] bf16
  ushort* wb  = hsb + (size_t)MROWS*DD;           // 3x [1024][1024] bf16
  ushort* qb  = wb  + (size_t)3*DD*DD;            // [B,H,T,HD]
  ushort* kb  = qb  + (size_t)MROWS*DD;
  ushort* vb  = kb  + (size_t)MROWS*DD;
  ushort* vtb = vb  + (size_t)MROWS*DD;           // [B,H,HD,T]

  cvt_bf16<<<(MROWS*DD/4)/256, 256, 0, stream>>>(hs, hsb, MROWS*DD/4);
  cvt_bf16<<<(DD*DD/4)/256, 256, 0, stream>>>(Wq, wb,            DD*DD/4);
  cvt_bf16<<<(DD*DD/4)/256, 256, 0, stream>>>(Wk, wb + DD*DD,    DD*DD/4);
  cvt_bf16<<<(DD*DD/4)/256, 256, 0, stream>>>(Wv, wb + 2*DD*DD,  DD*DD/4);

  qkv_gemm<<<dim3(MROWS/128, DD/128, 3), 256, 0, stream>>>(hsb, wb, bq, bk, bv, qb, kb, vb);
  vtranspose<<<dim3(TT/64, BB*HH), 256, 0, stream>>>(vb, vtb);
  attn_fwd<<<dim3(16, BB*HH), 256, 0, stream>>>(qb, kb, vtb, amask, out);
}

// Round 3
// 188.152 us; speedup vs baseline: 3.0163x; 1.9908x over previous
//
#include <hip/hip_runtime.h>
#include <hip/hip_bf16.h>
#include <stdint.h>

#define TT 2048
#define DD 1024
#define HH 16
#define HDIM 64
#define BB 4
#define MROWS 8192   // B*T
#define LOG2E 1.44269504088896340736f

typedef __attribute__((ext_vector_type(8))) short short8;
typedef __attribute__((ext_vector_type(4))) float floatx4;

__device__ __forceinline__ ushort f2bf(float f){
  uint32_t u = __builtin_bit_cast(uint32_t, f);
  u = u + 0x7fffu + ((u >> 16) & 1u);   // RNE
  return (ushort)(u >> 16);
}

__device__ __forceinline__ uint32_t cvtpk(float lo, float hi){
  uint32_t r;
  asm("v_cvt_pk_bf16_f32 %0, %1, %2" : "=v"(r) : "v"(lo), "v"(hi));
  return r;
}

__device__ __forceinline__ float exp2a(float x){
  float r;
  asm("v_exp_f32 %0, %1" : "=v"(r) : "v"(x));
  return r;
}

__device__ __forceinline__ void gld16(const void* g, void* l){
  __builtin_amdgcn_global_load_lds((const __attribute__((address_space(1))) uint32_t*)g,
                                   (__attribute__((address_space(3))) uint32_t*)l, 16, 0, 0);
}

// ---------------- fp32 -> bf16 conversion ----------------
__global__ void cvt_bf16(const float* __restrict__ src, ushort* __restrict__ dst, int n4){
  int i = blockIdx.x*blockDim.x + threadIdx.x;
  if (i < n4){
    float4 v = ((const float4*)src)[i];
    ushort4 o;
    o.x = f2bf(v.x); o.y = f2bf(v.y); o.z = f2bf(v.z); o.w = f2bf(v.w);
    ((ushort4*)dst)[i] = o;
  }
}

// ---------------- QKV projection GEMM: C = A @ W^T + b ----------------
// Q scaled by 0.125*log2e (attn runs softmax in exp2 domain).
// Q,K written [B,H,T,HD]; V written TRANSPOSED [B,H,HD,T].
__global__ __launch_bounds__(256) void qkv_gemm(
    const ushort* __restrict__ A, const ushort* __restrict__ Wall,
    const float* __restrict__ bq, const float* __restrict__ bk, const float* __restrict__ bv,
    ushort* __restrict__ Qo, ushort* __restrict__ Ko, ushort* __restrict__ Vo)
{
  __shared__ __align__(16) ushort sA[128*64];
  __shared__ __align__(16) ushort sB[128*64];
  const int mat = blockIdx.z;
  const ushort* W = Wall + (size_t)mat*DD*DD;
  const float* bias = (mat==0)? bq : (mat==1? bk : bv);
  ushort* out = (mat==0)? Qo : (mat==1? Ko : Vo);
  const float oscale = (mat==0)? 0.125f*LOG2E : 1.0f;
  const int m0 = blockIdx.x*128, n0 = blockIdx.y*128;
  const int tid = threadIdx.x, lane = tid & 63, wid = tid >> 6;
  const int wm = (wid>>1)*64, wn = (wid&1)*64;
  const int c = lane & 15, g = lane >> 4;
  const int srow = lane >> 3;
  const int scol = (lane & 7) * 8;

  floatx4 acc[4][4];
  #pragma unroll
  for (int i=0;i<4;i++)
    #pragma unroll
    for(int j=0;j<4;j++) acc[i][j] = (floatx4){0.f,0.f,0.f,0.f};

  for (int k0 = 0; k0 < DD; k0 += 64){
    #pragma unroll
    for (int j=0;j<4;j++){
      int chunk = wid*4 + j;
      int row = chunk*8 + srow;
      gld16(A + (size_t)(m0+row)*DD + k0 + scol, sA + chunk*512);
      gld16(W + (size_t)(n0+row)*DD + k0 + scol, sB + chunk*512);
    }
    __syncthreads();
    #pragma unroll
    for (int ch=0; ch<2; ++ch){
      short8 af[4], bfr[4];
      #pragma unroll
      for (int mf=0; mf<4; ++mf)
        af[mf] = *(const short8*)(sA + (wm + mf*16 + c)*64 + ch*32 + g*8);
      #pragma unroll
      for (int nf=0; nf<4; ++nf)
        bfr[nf] = *(const short8*)(sB + (wn + nf*16 + c)*64 + ch*32 + g*8);
      #pragma unroll
      for (int mf=0; mf<4; ++mf)
        #pragma unroll
        for (int nf=0; nf<4; ++nf)
          acc[mf][nf] = __builtin_amdgcn_mfma_f32_16x16x32_bf16(af[mf], bfr[nf], acc[mf][nf], 0,0,0);
    }
    __syncthreads();
  }
  #pragma unroll
  for (int nf=0; nf<4; ++nf){
    int col = n0 + wn + nf*16 + c;
    float bval = bias[col];
    int h = col >> 6, hd = col & 63;
    #pragma unroll
    for (int mf=0; mf<4; ++mf){
      int rowb = m0 + wm + mf*16 + g*4;
      int b = rowb >> 11, t = rowb & (TT-1);
      if (mat == 2){
        // transposed store: VT[b,h,hd,t..t+3], 4 consecutive t = 8B
        ushort4 st;
        st.x = f2bf(acc[mf][nf][0] + bval);
        st.y = f2bf(acc[mf][nf][1] + bval);
        st.z = f2bf(acc[mf][nf][2] + bval);
        st.w = f2bf(acc[mf][nf][3] + bval);
        *(ushort4*)(out + ((size_t)(b*HH + h)*HDIM + hd)*TT + t) = st;
      } else {
        #pragma unroll
        for (int r=0; r<4; ++r){
          float v = (acc[mf][nf][r] + bval) * oscale;
          out[((size_t)(b*HH + h)*TT + (t + r))*HDIM + hd] = f2bf(v);
        }
      }
    }
  }
}

// ---------------- causal flash attention (LDS-staged, pipelined) ----------------
// grid (8, B*H), 4 waves. Block x handles q-tiles {x, 15-x} of 128 rows each.
// Wave w owns q rows {base+w*16+c} (grp0) and {base+64+w*16+c} (grp1).
// K/VT tiles (64 kv) staged in LDS dbuf via global_load_lds, XOR-swizzled source,
// counted vmcnt(4) + raw barriers (T3/T4). amask pre-staged to LDS (exp2 domain).
__global__ __launch_bounds__(256,2) void attn_fwd(
    const ushort* __restrict__ Q, const ushort* __restrict__ K, const ushort* __restrict__ VT,
    const float* __restrict__ amask, float* __restrict__ O)
{
  __shared__ __align__(16) ushort sKt[2][4096];
  __shared__ __align__(16) ushort sVt[2][4096];
  __shared__ __align__(16) float  sAm[TT];
  __shared__ __align__(16) uint32_t sP[4][16*36];

  const int bh = blockIdx.y, b = bh >> 4, h = bh & 15;
  const int tid = threadIdx.x, lane = tid & 63, w = tid >> 6;
  const int c = lane & 15, g = lane >> 4;
  uint32_t* sPw = sP[w];

  const int qt1 = blockIdx.x, qt2 = 15 - qt1;
  const int nt1 = 2*qt1 + 2;
  const int ntot = 34;

  const char* Kbh = (const char*)(K  + (size_t)bh*TT*HDIM);
  const char* Vbh = (const char*)(VT + (size_t)bh*HDIM*TT);

  auto stage = [&](int f){
    int strip = (f >= nt1) ? 1 : 0;
    int it = strip ? f - nt1 : f;
    int kv0 = it*64;
    int buf = f & 1;
    int rlo = w*8 + (lane>>3);
    int colb = (lane & 7)*16;
    #pragma unroll
    for (int j=0;j<2;++j){
      int row = j*32 + rlo;
      int sw = (row & 7) << 4;
      gld16(Kbh + (size_t)(kv0+row)*128 + (colb ^ sw), &sKt[buf][j*2048 + w*512]);
      gld16(Vbh + (size_t)row*(TT*2) + (size_t)kv0*2 + (colb ^ sw), &sVt[buf][j*2048 + w*512]);
    }
  };

  short8 qf[2][2];
  auto loadq = [&](int qt_){
    #pragma unroll
    for (int grp=0; grp<2; ++grp){
      int qmy = qt_*128 + grp*64 + w*16 + c;
      #pragma unroll
      for (int ch=0; ch<2; ++ch)
        qf[grp][ch] = *(const short8*)(Q + ((size_t)bh*TT + qmy)*HDIM + ch*32 + g*8);
    }
  };

  floatx4 oacc[2][4];
  float mreg[2], lreg[2];
  auto reset_state = [&](){
    #pragma unroll
    for (int grp=0; grp<2; ++grp){
      mreg[grp] = -1e30f; lreg[grp] = 0.f;
      #pragma unroll
      for (int d=0; d<4; ++d) oacc[grp][d] = (floatx4){0.f,0.f,0.f,0.f};
    }
  };
  auto writeout = [&](int qt_){
    #pragma unroll
    for (int grp=0; grp<2; ++grp){
      int qmy = qt_*128 + grp*64 + w*16 + c;
      float rl = 1.f / lreg[grp];
      #pragma unroll
      for (int d=0; d<4; ++d){
        float4 st;
        st.x = oacc[grp][d][0]*rl; st.y = oacc[grp][d][1]*rl;
        st.z = oacc[grp][d][2]*rl; st.w = oacc[grp][d][3]*rl;
        *(float4*)(O + ((size_t)b*TT + qmy)*DD + h*HDIM + d*16 + g*4) = st;
      }
    }
  };

  // prologue: amask -> LDS (exp2 domain), Q frags, stage tile 0
  {
    const float* amb = amask + (size_t)b*TT;
    int i0 = tid*8;
    float4 a0 = *(const float4*)(amb + i0);
    float4 a1 = *(const float4*)(amb + i0 + 4);
    a0.x*=LOG2E; a0.y*=LOG2E; a0.z*=LOG2E; a0.w*=LOG2E;
    a1.x*=LOG2E; a1.y*=LOG2E; a1.z*=LOG2E; a1.w*=LOG2E;
    *(float4*)(sAm + i0) = a0;
    *(float4*)(sAm + i0 + 4) = a1;
  }
  loadq(qt1);
  reset_state();
  stage(0);
  __syncthreads();

  int qt = qt1, base = qt1*128;

  for (int f=0; f<ntot; ++f){
    const int strip = (f >= nt1) ? 1 : 0;
    const int it = strip ? f - nt1 : f;
    if (f == nt1){
      writeout(qt1);
      reset_state();
      loadq(qt2);
      qt = qt2; base = qt2*128;
    }
    if (f+1 < ntot){
      stage(f+1);
      asm volatile("s_waitcnt vmcnt(4)" ::: "memory");
    } else {
      asm volatile("s_waitcnt vmcnt(0)" ::: "memory");
    }
    __builtin_amdgcn_s_barrier();
    __builtin_amdgcn_sched_barrier(0);

    const int kv0 = it*64, buf = f & 1;
    const ushort* bK = sKt[buf];
    const ushort* bV = sVt[buf];
    const int rsw = (c & 7) << 3;   // element-unit read swizzle

    // shared LDS reads
    short8 kf[2][4];
    #pragma unroll
    for (int ch=0; ch<2; ++ch)
      #pragma unroll
      for (int nt=0; nt<4; ++nt)
        kf[ch][nt] = *(const short8*)(bK + (nt*16 + c)*64 + ((ch*32 + g*8) ^ rsw));
    float4 amv[4];
    #pragma unroll
    for (int nt=0; nt<4; ++nt)
      amv[nt] = *(const float4*)(sAm + kv0 + nt*16 + g*4);

    const bool act0 = (it <= 2*qt);
    short8 pbr[2][2];
    #pragma unroll
    for (int grp=0; grp<2; ++grp){
      if (grp==0 && !act0) continue;
      const int qrow0 = base + grp*64 + w*16;
      const int qmy = qrow0 + c;
      const bool caus = (kv0 + 63 > qrow0);
      floatx4 sacc[4];
      #pragma unroll
      for (int i=0;i<4;i++) sacc[i] = (floatx4){0.f,0.f,0.f,0.f};
      __builtin_amdgcn_s_setprio(1);
      #pragma unroll
      for (int ch=0; ch<2; ++ch)
        #pragma unroll
        for (int nt=0; nt<4; ++nt)
          sacc[nt] = __builtin_amdgcn_mfma_f32_16x16x32_bf16(kf[ch][nt], qf[grp][ch], sacc[nt], 0,0,0);
      __builtin_amdgcn_s_setprio(0);

      float p[4][4];
      float mx = -1e30f;
      #pragma unroll
      for (int nt=0; nt<4; ++nt)
        #pragma unroll
        for (int r=0; r<4; ++r){
          float s = sacc[nt][r] + ((const float*)&amv[nt])[r];
          if (caus){
            int kv = kv0 + nt*16 + g*4 + r;
            s = (kv > qmy) ? -1e30f : s;
          }
          p[nt][r] = s;
          mx = fmaxf(mx, s);
        }
      mx = fmaxf(mx, __shfl_xor(mx, 16));
      mx = fmaxf(mx, __shfl_xor(mx, 32));
      if (!__all(mx <= mreg[grp] + 8.f)){
        float mn = fmaxf(mreg[grp], mx);
        float sc = exp2a(mreg[grp] - mn);
        mreg[grp] = mn;
        lreg[grp] *= sc;
        #pragma unroll
        for (int d=0; d<4; ++d)
          #pragma unroll
          for (int r=0; r<4; ++r) oacc[grp][d][r] *= sc;
      }
      float ps = 0.f;
      #pragma unroll
      for (int nt=0; nt<4; ++nt)
        #pragma unroll
        for (int r=0; r<4; ++r){
          float e = exp2a(p[nt][r] - mreg[grp]);
          p[nt][r] = e;
          ps += e;
        }
      ps += __shfl_xor(ps, 16);
      ps += __shfl_xor(ps, 32);
      lreg[grp] += ps;
      // pack P -> bf16, bounce through wave-private LDS
      #pragma unroll
      for (int nt=0; nt<4; ++nt){
        uint2 pk;
        pk.x = cvtpk(p[nt][0], p[nt][1]);
        pk.y = cvtpk(p[nt][2], p[nt][3]);
        *(uint2*)(sPw + 36*c + 8*nt + 2*g) = pk;
      }
      pbr[grp][0] = *(const short8*)(sPw + 36*c + 4*g);
      pbr[grp][1] = *(const short8*)(sPw + 36*c + 16 + 4*g);
    }

    short8 vf[2][4];
    #pragma unroll
    for (int ch=0; ch<2; ++ch)
      #pragma unroll
      for (int d=0; d<4; ++d)
        vf[ch][d] = *(const short8*)(bV + (d*16 + c)*64 + ((ch*32 + g*8) ^ rsw));
    __builtin_amdgcn_s_setprio(1);
    #pragma unroll
    for (int grp=0; grp<2; ++grp){
      if (grp==0 && !act0) continue;
      #pragma unroll
      for (int d=0; d<4; ++d)
        #pragma unroll
        for (int ch=0; ch<2; ++ch)
          oacc[grp][d] = __builtin_amdgcn_mfma_f32_16x16x32_bf16(vf[ch][d], pbr[grp][ch], oacc[grp][d], 0,0,0);
    }
    __builtin_amdgcn_s_setprio(0);

    __builtin_amdgcn_sched_barrier(0);
    __builtin_amdgcn_s_barrier();
  }
  writeout(qt2);
}

extern "C" void kernel_launch(void* const* d_in, const int* in_sizes, int n_in,
                              void* d_out, int out_size, void* d_ws, size_t ws_size,
                              hipStream_t stream){
  const float* hs    = (const float*)d_in[0];
  const float* amask = (const float*)d_in[1];
  const float* Wq    = (const float*)d_in[2];
  const float* bq    = (const float*)d_in[3];
  const float* Wk    = (const float*)d_in[4];
  const float* bk    = (const float*)d_in[5];
  const float* Wv    = (const float*)d_in[6];
  const float* bv    = (const float*)d_in[7];
  float* out = (float*)d_out;

  ushort* hsb = (ushort*)d_ws;                    // [8192][1024] bf16
  ushort* wb  = hsb + (size_t)MROWS*DD;           // 3x [1024][1024] bf16
  ushort* qb  = wb  + (size_t)3*DD*DD;            // [B,H,T,HD]
  ushort* kb  = qb  + (size_t)MROWS*DD;           // [B,H,T,HD]
  ushort* vtb = kb  + (size_t)MROWS*DD;           // [B,H,HD,T] (written directly by qkv_gemm)

  cvt_bf16<<<(MROWS*DD/4)/256, 256, 0, stream>>>(hs, hsb, MROWS*DD/4);
  cvt_bf16<<<(DD*DD/4)/256, 256, 0, stream>>>(Wq, wb,            DD*DD/4);
  cvt_bf16<<<(DD*DD/4)/256, 256, 0, stream>>>(Wk, wb + DD*DD,    DD*DD/4);
  cvt_bf16<<<(DD*DD/4)/256, 256, 0, stream>>>(Wv, wb + 2*DD*DD,  DD*DD/4);

  qkv_gemm<<<dim3(MROWS/128, DD/128, 3), 256, 0, stream>>>(hsb, wb, bq, bk, bv, qb, kb, vtb);
  attn_fwd<<<dim3(8, BB*HH), 256, 0, stream>>>(qb, kb, vtb, amask, out);
}